// Round 6
// baseline (136.199 us; speedup 1.0000x reference)
//
#include <hip/hip_runtime.h>
#include <math.h>

// Problem constants
#define HN 8
#define DK 64
#define LQ 4096
#define LKV 1024
#define DMODEL 512
#define BATCH 2

typedef unsigned short u16;
typedef unsigned int u32;
typedef __attribute__((ext_vector_type(8))) __bf16 bf16x8;
typedef __attribute__((ext_vector_type(4))) float f32x4;
typedef __attribute__((ext_vector_type(8))) u16 u16x8;

// fp32 -> bf16 round-to-nearest-even (finite inputs only)
__device__ __forceinline__ u16 f2bf(float f) {
    u32 u = __float_as_uint(f);
    u = u + 0x7fffu + ((u >> 16) & 1u);
    return (u16)(u >> 16);
}
__device__ __forceinline__ float bf2f(u16 u) {
    return __uint_as_float(((u32)u) << 16);
}

// async 16B global -> LDS (wave-uniform LDS base; HW writes base + lane*16)
__device__ __forceinline__ void gl_lds16(const u16* g, u16* l) {
    __builtin_amdgcn_global_load_lds((const __attribute__((address_space(1))) u32*)g,
                                     (__attribute__((address_space(3))) u32*)l, 16, 0, 0);
}

// ---------------------------------------------------------------------------
// Projection GEMM with inline fp32->bf16 A-staging.
// C[M x 512] = A_f32[M x 512] * W, Bt = W^T bf16 [n][k].
// Tile 128x128, BK=32, 4 waves 2x2, each wave 4x4 of 16x16x32 MFMA.
// A: float4 loads -> cvt -> ds_write_b128 into stride-40 LDS (16B-aligned
//    rows; rows r and r+8 share a bank window -> 2-way aliasing = free).
// B: gl_lds width-16 from pre-transposed bf16 weights, stride-32 + XOR
//    chunk swizzle (R3-proven path).
// ---------------------------------------------------------------------------
__global__ __launch_bounds__(256) void proj_inline(const float* __restrict__ q,
                                                   const float* __restrict__ k,
                                                   const float* __restrict__ v,
                                                   const u16* __restrict__ wqt,
                                                   const u16* __restrict__ wkt,
                                                   const u16* __restrict__ wvt,
                                                   u16* __restrict__ Qb,
                                                   u16* __restrict__ Kb,
                                                   u16* __restrict__ Vb) {
    __shared__ u16 As[128 * 40];   // stride 40 (80 B rows), no swizzle
    __shared__ u16 Bs[128 * 32];   // stride 32, XOR chunk swizzle

    const int idx = blockIdx.x;
    const float* A;
    const u16* Bt;
    u16* Cp;
    int bx, by;
    if (idx < 256)      { A = q; Bt = wqt; Cp = Qb; bx = idx & 3; by = idx >> 2; }
    else if (idx < 320) { A = k; Bt = wkt; Cp = Kb; bx = (idx - 256) & 3; by = (idx - 256) >> 2; }
    else                { A = v; Bt = wvt; Cp = Vb; bx = (idx - 320) & 3; by = (idx - 320) >> 2; }

    const int tid = threadIdx.x;
    const int lane = tid & 63;
    const int wave = tid >> 6;
    const int wm = (wave >> 1) * 64;
    const int wn = (wave & 1) * 64;
    const int quad = lane >> 4;
    const int l16 = lane & 15;
    const size_t m0 = (size_t)by * 128;
    const size_t n0 = (size_t)bx * 128;

    f32x4 acc[4][4] = {};

    for (int k0 = 0; k0 < 512; k0 += 32) {
        // ---- B stage: gl_lds, 512 chunks, 2/thread ----
#pragma unroll
        for (int i = 0; i < 2; ++i) {
            const int id = i * 256 + tid;
            const int r = id >> 2;
            const int cs = id & 3;
            const int c = cs ^ ((r >> 1) & 3);
            gl_lds16(&Bt[(n0 + r) * 512 + k0 + c * 8], &Bs[(size_t)(i * 256 + wave * 64) * 8]);
        }
        // ---- A stage: fp32 load + cvt + ds_write_b128, 512 chunks, 2/thread ----
#pragma unroll
        for (int i = 0; i < 2; ++i) {
            const int id = i * 256 + tid;
            const int r = id >> 2;           // row 0..127
            const int c = id & 3;            // k-chunk 0..3 (logical, no swizzle)
            const float4* ap = (const float4*)&A[(m0 + r) * 512 + k0 + c * 8];
            const float4 a0 = ap[0];
            const float4 a1 = ap[1];
            u16x8 w;
            w[0] = f2bf(a0.x); w[1] = f2bf(a0.y); w[2] = f2bf(a0.z); w[3] = f2bf(a0.w);
            w[4] = f2bf(a1.x); w[5] = f2bf(a1.y); w[6] = f2bf(a1.z); w[7] = f2bf(a1.w);
            *(u16x8*)&As[r * 40 + c * 8] = w;
        }
        __syncthreads();

        bf16x8 af[4], bfr[4];
#pragma unroll
        for (int i = 0; i < 4; ++i) {
            const int ra = wm + i * 16 + l16;
            af[i] = *(const bf16x8*)&As[ra * 40 + quad * 8];
            const int rb = wn + i * 16 + l16;
            const int cb = quad ^ ((rb >> 1) & 3);
            bfr[i] = *(const bf16x8*)&Bs[rb * 32 + cb * 8];
        }
#pragma unroll
        for (int i = 0; i < 4; ++i)
#pragma unroll
            for (int j = 0; j < 4; ++j)
                acc[i][j] = __builtin_amdgcn_mfma_f32_16x16x32_bf16(af[i], bfr[j], acc[i][j], 0, 0, 0);
        __syncthreads();
    }

    // Epilogue: C/D layout col = lane&15, row = quad*4 + reg; bf16 out
#pragma unroll
    for (int i = 0; i < 4; ++i) {
#pragma unroll
        for (int j = 0; j < 4; ++j) {
            const size_t row = m0 + wm + i * 16 + quad * 4;
            const size_t col = n0 + wn + j * 16 + l16;
#pragma unroll
            for (int t = 0; t < 4; ++t)
                Cp[(row + t) * 512 + col] = f2bf(acc[i][j][t]);
        }
    }
}

// ---------------------------------------------------------------------------
// Output projection: both operands bf16 via gl_lds (R3 gemm_body verbatim).
// ---------------------------------------------------------------------------
__global__ __launch_bounds__(256) void gemm_out(const u16* __restrict__ A,
                                                const u16* __restrict__ Bt,
                                                float* __restrict__ C) {
    __shared__ u16 As[128 * 32];
    __shared__ u16 Bs[128 * 32];

    const int tid = threadIdx.x;
    const int lane = tid & 63;
    const int wave = tid >> 6;
    const int wm = (wave >> 1) * 64;
    const int wn = (wave & 1) * 64;
    const int quad = lane >> 4;
    const int l16 = lane & 15;
    const size_t m0 = (size_t)(blockIdx.x >> 2) * 128;
    const size_t n0 = (size_t)(blockIdx.x & 3) * 128;

    f32x4 acc[4][4] = {};

    for (int k0 = 0; k0 < 512; k0 += 32) {
#pragma unroll
        for (int i = 0; i < 2; ++i) {
            const int id = i * 256 + tid;
            const int r = id >> 2;
            const int cs = id & 3;
            const int c = cs ^ ((r >> 1) & 3);
            gl_lds16(&A[(m0 + r) * 512 + k0 + c * 8], &As[(size_t)(i * 256 + wave * 64) * 8]);
            gl_lds16(&Bt[(n0 + r) * 512 + k0 + c * 8], &Bs[(size_t)(i * 256 + wave * 64) * 8]);
        }
        __syncthreads();

        bf16x8 af[4], bfr[4];
#pragma unroll
        for (int i = 0; i < 4; ++i) {
            const int ra = wm + i * 16 + l16;
            const int ca = quad ^ ((ra >> 1) & 3);
            af[i] = *(const bf16x8*)&As[ra * 32 + ca * 8];
            const int rb = wn + i * 16 + l16;
            const int cb = quad ^ ((rb >> 1) & 3);
            bfr[i] = *(const bf16x8*)&Bs[rb * 32 + cb * 8];
        }
#pragma unroll
        for (int i = 0; i < 4; ++i)
#pragma unroll
            for (int j = 0; j < 4; ++j)
                acc[i][j] = __builtin_amdgcn_mfma_f32_16x16x32_bf16(af[i], bfr[j], acc[i][j], 0, 0, 0);
        __syncthreads();
    }

#pragma unroll
    for (int i = 0; i < 4; ++i) {
#pragma unroll
        for (int j = 0; j < 4; ++j) {
            const size_t row = m0 + wm + i * 16 + quad * 4;
            const size_t col = n0 + wn + j * 16 + l16;
#pragma unroll
            for (int t = 0; t < 4; ++t)
                C[(row + t) * 512 + col] = acc[i][j][t];
        }
    }
}

// ---------------------------------------------------------------------------
// Weight prep only: transpose-convert the four 512x512 weights to bf16 [n][k].
// Flat 1024-block grid: z = bid>>8 selects weight, t = bid&255 a 32x32 tile.
// ---------------------------------------------------------------------------
__global__ __launch_bounds__(256) void prep_w(const float* __restrict__ Wq,
                                              const float* __restrict__ Wk,
                                              const float* __restrict__ Wv,
                                              const float* __restrict__ Wout,
                                              u16* __restrict__ wqt, u16* __restrict__ wkt,
                                              u16* __restrict__ wvt, u16* __restrict__ wot) {
    __shared__ float tbuf[32][33];
    const int bid = blockIdx.x;
    const int tid = threadIdx.x;
    const int z = bid >> 8;
    const int t = bid & 255;
    const float* W = (z == 0) ? Wq : (z == 1) ? Wk : (z == 2) ? Wv : Wout;
    u16* O = (z == 0) ? wqt : (z == 1) ? wkt : (z == 2) ? wvt : wot;
    const int tx = tid & 31;
    const int ty = tid >> 5;            // 0..7
    const int x = (t & 15) * 32 + tx;   // source col n
    const int y0 = (t >> 4) * 32;       // source row k base
#pragma unroll
    for (int i = ty; i < 32; i += 8) tbuf[i][tx] = W[(size_t)(y0 + i) * 512 + x];
    __syncthreads();
#pragma unroll
    for (int i = ty; i < 32; i += 8)
        O[(size_t)((t & 15) * 32 + i) * 512 + y0 + tx] = f2bf(tbuf[tx][i]);
}

// ---------------------------------------------------------------------------
// Sparse sliding-window attention, bf16 in, fp32 compute, bf16 ctx out.
// For query c: fd = floor((63-c)/4); KV col(r) = r - fd, valid iff r >= fd.
// 256 queries/block, 80-row window in LDS (R3-proven version).
// ---------------------------------------------------------------------------
__global__ __launch_bounds__(256) void attn_f32(const u16* __restrict__ Q,
                                                const u16* __restrict__ K,
                                                const u16* __restrict__ V,
                                                u16* __restrict__ ctx) {
    __shared__ float Ks[80][68];
    __shared__ float Vs[80][68];

    const int tid = threadIdx.x;
    const int c0 = blockIdx.x * 256;
    const int h = blockIdx.y;
    const int b = blockIdx.z;

    const int fd_c0 = (63 - c0) >> 2;
    const int win_lo = (fd_c0 < 0) ? -fd_c0 : 0;

    for (int i = tid; i < 80 * 8; i += 256) {
        int row = i >> 3;
        int d8 = i & 7;
        int col = win_lo + row;
        if (col < LKV) {
            size_t base = ((size_t)(b * LKV + col)) * DMODEL + h * DK + d8 * 8;
            u16x8 k8 = *(const u16x8*)&K[base];
            u16x8 v8 = *(const u16x8*)&V[base];
            *(float4*)&Ks[row][d8 * 8]     = make_float4(bf2f(k8[0]), bf2f(k8[1]), bf2f(k8[2]), bf2f(k8[3]));
            *(float4*)&Ks[row][d8 * 8 + 4] = make_float4(bf2f(k8[4]), bf2f(k8[5]), bf2f(k8[6]), bf2f(k8[7]));
            *(float4*)&Vs[row][d8 * 8]     = make_float4(bf2f(v8[0]), bf2f(v8[1]), bf2f(v8[2]), bf2f(v8[3]));
            *(float4*)&Vs[row][d8 * 8 + 4] = make_float4(bf2f(v8[4]), bf2f(v8[5]), bf2f(v8[6]), bf2f(v8[7]));
        }
    }
    __syncthreads();

    const int c = c0 + tid;
    const int fd = (63 - c) >> 2;

    float qreg[64];
    const u16* qp = &Q[((size_t)(b * LQ + c)) * DMODEL + h * DK];
#pragma unroll
    for (int i = 0; i < 8; ++i) {
        u16x8 t8 = *(const u16x8*)&qp[i * 8];
#pragma unroll
        for (int j = 0; j < 8; ++j) qreg[i * 8 + j] = bf2f(t8[j]);
    }

    float sc[16];
    float mx = -3.0e38f;
#pragma unroll
    for (int r = 0; r < 16; ++r) {
        int col = r - fd;
        if (col < 0) col = 0;
        const float* kr = &Ks[col - win_lo][0];
        float s = 0.f;
#pragma unroll
        for (int i = 0; i < 64; ++i) s = fmaf(qreg[i], kr[i], s);
        s *= 0.125f;
        sc[r] = (r >= fd) ? s : -1.0e30f;
        mx = fmaxf(mx, sc[r]);
    }

    float sum = 0.f;
#pragma unroll
    for (int r = 0; r < 16; ++r) {
        sc[r] = __expf(sc[r] - mx);
        sum += sc[r];
    }
    const float inv = 1.0f / sum;

    float acc[64];
#pragma unroll
    for (int i = 0; i < 64; ++i) acc[i] = 0.f;
#pragma unroll
    for (int r = 0; r < 16; ++r) {
        const float w = sc[r] * inv;
        int col = r - fd;
        if (col < 0) col = 0;
        const float* vr = &Vs[col - win_lo][0];
#pragma unroll
        for (int i = 0; i < 64; ++i) acc[i] = fmaf(w, vr[i], acc[i]);
    }

    u16* cp = &ctx[((size_t)(b * LQ + c)) * DMODEL + h * DK];
#pragma unroll
    for (int i = 0; i < 8; ++i) {
        u16x8 o;
#pragma unroll
        for (int j = 0; j < 8; ++j) o[j] = f2bf(acc[i * 8 + j]);
        *(u16x8*)&cp[i * 8] = o;
    }
}

// ---------------------------------------------------------------------------
extern "C" void kernel_launch(void* const* d_in, const int* in_sizes, int n_in,
                              void* d_out, int out_size, void* d_ws, size_t ws_size,
                              hipStream_t stream) {
    const float* q    = (const float*)d_in[0];
    const float* k    = (const float*)d_in[1];
    const float* v    = (const float*)d_in[2];
    const float* Wq   = (const float*)d_in[3];
    const float* Wk   = (const float*)d_in[4];
    const float* Wv   = (const float*)d_in[5];
    const float* Wout = (const float*)d_in[6];
    float* out = (float*)d_out;

    const size_t NQ = (size_t)BATCH * LQ * DMODEL;   // 4,194,304
    const size_t NK = (size_t)BATCH * LKV * DMODEL;  // 1,048,576
    const size_t NW = (size_t)DMODEL * DMODEL;       //   262,144

    // Workspace layout (all bf16 u16)
    u16* Qb  = (u16*)d_ws;      // bf16 projections
    u16* Kb  = Qb + NQ;
    u16* Vb  = Kb + NK;
    u16* cb  = Vb + NK;         // bf16 ctx
    u16* wqt = cb + NQ;         // bf16 transposed weights
    u16* wkt = wqt + NW;
    u16* wvt = wkt + NW;
    u16* wot = wvt + NW;

    // 1) weight transpose-convert only (tiny)
    prep_w<<<dim3(1024), dim3(256), 0, stream>>>(Wq, Wk, Wv, Wout, wqt, wkt, wvt, wot);

    // 2) fused Q/K/V projections, inline fp32 A staging (bf16 out)
    proj_inline<<<dim3(384), dim3(256), 0, stream>>>(q, k, v, wqt, wkt, wvt, Qb, Kb, Vb);

    // 3) attention (bf16 in, fp32 compute, bf16 ctx)
    attn_f32<<<dim3(LQ / 256, HN, BATCH), dim3(256), 0, stream>>>(Qb, Kb, Vb, cb);

    // 4) output projection (fp32 out)
    gemm_out<<<dim3(256), dim3(256), 0, stream>>>(cb, wot, out);
}